// Round 1
// baseline (2352.920 us; speedup 1.0000x reference)
//
#include <hip/hip_runtime.h>
#include <hip/hip_bf16.h>

#define V_N 100000
#define E_N 800000
#define D_N 128
#define META_N 10
#define EF_N 16
#define NVEH 16
#define LN_EPS 1e-5f

// ---------------- count in-degree ----------------
__global__ __launch_bounds__(256) void k_count(const int* __restrict__ dst, int* __restrict__ cnt) {
    int i = blockIdx.x * blockDim.x + threadIdx.x;
    if (i < E_N) atomicAdd(&cnt[dst[i]], 1);
}

// ---------------- node projection: h = concat(Z, meta) @ Wp + bp ----------------
// 16 nodes per block, 128 threads; input rows staged in LDS, broadcast-read.
__global__ __launch_bounds__(128) void k_nodeproj(const float* __restrict__ Z, const float* __restrict__ meta,
                                                  const float* __restrict__ W, const float* __restrict__ b,
                                                  float* __restrict__ h) {
    __shared__ float rows[16][140];   // 138 used; stride 140 keeps rows 16B-aligned
    const int base = blockIdx.x * 16;
    const int tid = threadIdx.x;
    for (int idx = tid; idx < 16 * 138; idx += 128) {
        int r = idx / 138, c = idx - r * 138;
        int v = base + r;
        rows[r][c] = (c < 128) ? Z[(size_t)v * 128 + c] : meta[(size_t)v * 10 + (c - 128)];
    }
    __syncthreads();
    const int j = tid;
    float acc[16];
    float bj = b[j];
#pragma unroll
    for (int r = 0; r < 16; ++r) acc[r] = bj;
    const float4* r4 = (const float4*)&rows[0][0];
    for (int k4 = 0; k4 < 34; ++k4) {           // k = 0..135
        float w0 = W[(k4 * 4 + 0) * 128 + j];
        float w1 = W[(k4 * 4 + 1) * 128 + j];
        float w2 = W[(k4 * 4 + 2) * 128 + j];
        float w3 = W[(k4 * 4 + 3) * 128 + j];
#pragma unroll
        for (int r = 0; r < 16; ++r) {
            float4 rv = r4[r * 35 + k4];
            acc[r] = fmaf(rv.x, w0, acc[r]);
            acc[r] = fmaf(rv.y, w1, acc[r]);
            acc[r] = fmaf(rv.z, w2, acc[r]);
            acc[r] = fmaf(rv.w, w3, acc[r]);
        }
    }
    // tail k = 136, 137
    {
        float w0 = W[136 * 128 + j];
        float w1 = W[137 * 128 + j];
#pragma unroll
        for (int r = 0; r < 16; ++r) {
            acc[r] = fmaf(rows[r][136], w0, acc[r]);
            acc[r] = fmaf(rows[r][137], w1, acc[r]);
        }
    }
#pragma unroll
    for (int r = 0; r < 16; ++r) h[(size_t)(base + r) * 128 + j] = acc[r];
}

// ---------------- t = h @ W1[:128] + b1 (per layer) ----------------
__global__ __launch_bounds__(128) void k_matvec128(const float* __restrict__ in, const float* __restrict__ W,
                                                   const float* __restrict__ b, float* __restrict__ out) {
    __shared__ float rows[16][128];
    const int base = blockIdx.x * 16;
    const int tid = threadIdx.x;
    for (int idx = tid; idx < 16 * 128; idx += 128) {
        int r = idx >> 7, c = idx & 127;
        rows[r][c] = in[(size_t)(base + r) * 128 + c];
    }
    __syncthreads();
    const int j = tid;
    float acc[16];
    float bj = b[j];
#pragma unroll
    for (int r = 0; r < 16; ++r) acc[r] = bj;
    const float4* r4 = (const float4*)&rows[0][0];
    for (int k4 = 0; k4 < 32; ++k4) {
        float w0 = W[(k4 * 4 + 0) * 128 + j];
        float w1 = W[(k4 * 4 + 1) * 128 + j];
        float w2 = W[(k4 * 4 + 2) * 128 + j];
        float w3 = W[(k4 * 4 + 3) * 128 + j];
#pragma unroll
        for (int r = 0; r < 16; ++r) {
            float4 rv = r4[r * 32 + k4];
            acc[r] = fmaf(rv.x, w0, acc[r]);
            acc[r] = fmaf(rv.y, w1, acc[r]);
            acc[r] = fmaf(rv.z, w2, acc[r]);
            acc[r] = fmaf(rv.w, w3, acc[r]);
        }
    }
#pragma unroll
    for (int r = 0; r < 16; ++r) out[(size_t)(base + r) * 128 + j] = acc[r];
}

// ---------------- edge kernel: S[dst] += relu(t[src] + ea @ W1a) ----------------
// 256 threads = 2 edge-slots x 128 lanes; 32 edges per block.
__global__ __launch_bounds__(256) void k_edge(const float* __restrict__ t, const float* __restrict__ ea,
                                              const int* __restrict__ src, const int* __restrict__ dst,
                                              const float* __restrict__ W1a, float* __restrict__ S) {
    __shared__ float w1a[16 * 128];
    const int tid = threadIdx.x;
    for (int idx = tid; idx < 16 * 128; idx += 256) w1a[idx] = W1a[idx];
    __syncthreads();
    const int j = tid & 127;
    const int es = tid >> 7;
    const long base = (long)blockIdx.x * 32;
    for (int i = 0; i < 16; ++i) {
        long e = base + i * 2 + es;
        int s = src[e];
        int d = dst[e];
        const float4* a4 = (const float4*)(ea + (size_t)e * 16);
        float4 a0 = a4[0], a1 = a4[1], a2 = a4[2], a3 = a4[3];
        float pre = t[(size_t)s * 128 + j];
        pre = fmaf(a0.x, w1a[0 * 128 + j], pre);
        pre = fmaf(a0.y, w1a[1 * 128 + j], pre);
        pre = fmaf(a0.z, w1a[2 * 128 + j], pre);
        pre = fmaf(a0.w, w1a[3 * 128 + j], pre);
        pre = fmaf(a1.x, w1a[4 * 128 + j], pre);
        pre = fmaf(a1.y, w1a[5 * 128 + j], pre);
        pre = fmaf(a1.z, w1a[6 * 128 + j], pre);
        pre = fmaf(a1.w, w1a[7 * 128 + j], pre);
        pre = fmaf(a2.x, w1a[8 * 128 + j], pre);
        pre = fmaf(a2.y, w1a[9 * 128 + j], pre);
        pre = fmaf(a2.z, w1a[10 * 128 + j], pre);
        pre = fmaf(a2.w, w1a[11 * 128 + j], pre);
        pre = fmaf(a3.x, w1a[12 * 128 + j], pre);
        pre = fmaf(a3.y, w1a[13 * 128 + j], pre);
        pre = fmaf(a3.z, w1a[14 * 128 + j], pre);
        pre = fmaf(a3.w, w1a[15 * 128 + j], pre);
        float m = fmaxf(pre, 0.f);
        atomicAdd(&S[(size_t)d * 128 + j], m);
    }
}

// ---------------- node update: h = LN(h + (S@W2)/cnt + b2*mask) ----------------
// 256 threads = 4 waves; W2 (64KB f32) in LDS; each wave does 4 nodes/iter.
__global__ __launch_bounds__(256) void k_node_update(const float* __restrict__ S, const int* __restrict__ cnt,
                                                     const float* __restrict__ W2, const float* __restrict__ b2,
                                                     const float* __restrict__ g, const float* __restrict__ bt,
                                                     float* __restrict__ h) {
    __shared__ float w2[128 * 128];   // 64 KB
    const int tid = threadIdx.x;
    for (int idx = tid; idx < 16384; idx += 256) w2[idx] = W2[idx];
    __syncthreads();
    const int lane = tid & 63;
    const int wid = tid >> 6;
    const float g0 = g[lane], g1 = g[lane + 64];
    const float bt0 = bt[lane], bt1 = bt[lane + 64];
    const float b20 = b2[lane], b21 = b2[lane + 64];
    const int gw = blockIdx.x * 4 + wid;
    const int nw = gridDim.x * 4;
    for (int vb = gw * 4; vb < V_N; vb += nw * 4) {
        float ya[4], yb[4];
#pragma unroll
        for (int n = 0; n < 4; ++n) {
            ya[n] = S[(size_t)(vb + n) * 128 + lane];
            yb[n] = S[(size_t)(vb + n) * 128 + 64 + lane];
        }
        float acca[4] = {0.f, 0.f, 0.f, 0.f};
        float accb[4] = {0.f, 0.f, 0.f, 0.f};
#pragma unroll
        for (int k = 0; k < 64; ++k) {
            float wA = w2[k * 128 + lane];
            float wB = w2[k * 128 + 64 + lane];
#pragma unroll
            for (int n = 0; n < 4; ++n) {
                float s = __shfl(ya[n], k);
                acca[n] = fmaf(s, wA, acca[n]);
                accb[n] = fmaf(s, wB, accb[n]);
            }
        }
#pragma unroll
        for (int k = 0; k < 64; ++k) {
            float wA = w2[(k + 64) * 128 + lane];
            float wB = w2[(k + 64) * 128 + 64 + lane];
#pragma unroll
            for (int n = 0; n < 4; ++n) {
                float s = __shfl(yb[n], k);
                acca[n] = fmaf(s, wA, acca[n]);
                accb[n] = fmaf(s, wB, accb[n]);
            }
        }
#pragma unroll
        for (int n = 0; n < 4; ++n) {
            int v = vb + n;
            int c = cnt[v];
            float inv = 1.f / (float)(c > 1 ? c : 1);
            float sc = (c > 0) ? 1.f : 0.f;
            float x0 = h[(size_t)v * 128 + lane] + acca[n] * inv + b20 * sc;
            float x1 = h[(size_t)v * 128 + 64 + lane] + accb[n] * inv + b21 * sc;
            float sum = x0 + x1;
#pragma unroll
            for (int o = 32; o > 0; o >>= 1) sum += __shfl_xor(sum, o);
            float mean = sum * (1.f / 128.f);
            float d0 = x0 - mean, d1 = x1 - mean;
            float vs = d0 * d0 + d1 * d1;
#pragma unroll
            for (int o = 32; o > 0; o >>= 1) vs += __shfl_xor(vs, o);
            float r = rsqrtf(vs * (1.f / 128.f) + LN_EPS);
            h[(size_t)v * 128 + lane] = d0 * r * g0 + bt0;
            h[(size_t)v * 128 + 64 + lane] = d1 * r * g1 + bt1;
        }
    }
}

// ---------------- final: out = LN(h[cur] + props MLP) ----------------
__global__ __launch_bounds__(128) void k_final(const float* __restrict__ h, const int* __restrict__ cur,
                                               const float* __restrict__ veh,
                                               const float* __restrict__ pw1, const float* __restrict__ pb1,
                                               const float* __restrict__ pw2, const float* __restrict__ pb2,
                                               const float* __restrict__ g, const float* __restrict__ bt,
                                               float* __restrict__ out) {
    __shared__ float hid[128];
    __shared__ float red[2];
    const int i = blockIdx.x;
    const int j = threadIdx.x;
    float a = pb1[j];
#pragma unroll
    for (int f = 0; f < 8; ++f) a = fmaf(veh[i * 8 + f], pw1[f * 128 + j], a);
    hid[j] = fmaxf(a, 0.f);
    __syncthreads();
    float o = pb2[j] + h[(size_t)cur[i] * 128 + j];
    for (int k = 0; k < 128; ++k) o = fmaf(hid[k], pw2[k * 128 + j], o);
    const int lane = j & 63, wid = j >> 6;
    float s = o;
#pragma unroll
    for (int off = 32; off > 0; off >>= 1) s += __shfl_xor(s, off);
    if (lane == 0) red[wid] = s;
    __syncthreads();
    float mean = (red[0] + red[1]) * (1.f / 128.f);
    __syncthreads();
    float d = o - mean;
    float vv = d * d;
#pragma unroll
    for (int off = 32; off > 0; off >>= 1) vv += __shfl_xor(vv, off);
    if (lane == 0) red[wid] = vv;
    __syncthreads();
    float var = (red[0] + red[1]) * (1.f / 128.f);
    float r = rsqrtf(var + LN_EPS);
    out[i * 128 + j] = d * r * g[j] + bt[j];
}

extern "C" void kernel_launch(void* const* d_in, const int* in_sizes, int n_in,
                              void* d_out, int out_size, void* d_ws, size_t ws_size,
                              hipStream_t stream) {
    const float* Z    = (const float*)d_in[0];
    const float* meta = (const float*)d_in[1];
    const float* veh  = (const float*)d_in[2];
    const float* ea   = (const float*)d_in[3];
    const int*   esrc = (const int*)d_in[4];
    const int*   edst = (const int*)d_in[5];
    const int*   cur  = (const int*)d_in[6];
    const float* npw  = (const float*)d_in[7];
    const float* npb  = (const float*)d_in[8];
    const float* w1   = (const float*)d_in[9];
    const float* b1   = (const float*)d_in[10];
    const float* w2   = (const float*)d_in[11];
    const float* b2   = (const float*)d_in[12];
    const float* lng  = (const float*)d_in[13];
    const float* lnb  = (const float*)d_in[14];
    const float* pw1  = (const float*)d_in[15];
    const float* pb1  = (const float*)d_in[16];
    const float* pw2  = (const float*)d_in[17];
    const float* pb2  = (const float*)d_in[18];
    const float* rog  = (const float*)d_in[19];
    const float* rob  = (const float*)d_in[20];

    float* h = (float*)d_ws;
    float* t = h + (size_t)V_N * 128;
    float* S = t + (size_t)V_N * 128;
    int* cnt = (int*)(S + (size_t)V_N * 128);
    float* out = (float*)d_out;

    hipMemsetAsync(cnt, 0, V_N * sizeof(int), stream);
    k_count<<<(E_N + 255) / 256, 256, 0, stream>>>(edst, cnt);
    k_nodeproj<<<V_N / 16, 128, 0, stream>>>(Z, meta, npw, npb, h);

    for (int l = 0; l < 2; ++l) {
        const float* W1b = w1 + (size_t)l * 144 * 128;      // rows 0..127 (h part)
        const float* W1a = W1b + 128 * 128;                  // rows 128..143 (edge_attr part)
        k_matvec128<<<V_N / 16, 128, 0, stream>>>(h, W1b, b1 + l * 128, t);
        hipMemsetAsync(S, 0, (size_t)V_N * 128 * sizeof(float), stream);
        k_edge<<<E_N / 32, 256, 0, stream>>>(t, ea, esrc, edst, W1a, S);
        k_node_update<<<1024, 256, 0, stream>>>(S, cnt, w2 + (size_t)l * 128 * 128, b2 + l * 128,
                                                lng + l * 128, lnb + l * 128, h);
    }
    k_final<<<NVEH, 128, 0, stream>>>(h, cur, veh, pw1, pb1, pw2, pb2, rog, rob, out);
}

// Round 2
// 861.693 us; speedup vs baseline: 2.7306x; 2.7306x over previous
//
#include <hip/hip_runtime.h>
#include <hip/hip_bf16.h>

#define V_N 100000
#define VP  100096          // padded to multiple of 64
#define E_N 800000
#define NVEH 16
#define LN_EPS 1e-5f
#define NTILES (VP / 64)    // 1564

typedef unsigned int uint;
typedef unsigned short ushort;
typedef __attribute__((ext_vector_type(8))) short bf8_t;   // 8 bf16 in 4 VGPRs
typedef __attribute__((ext_vector_type(4))) float f4_t;

__device__ __forceinline__ float bf2f(ushort u) {
    union { uint i; float f; } c; c.i = ((uint)u) << 16; return c.f;
}
__device__ __forceinline__ ushort f2bf(float f) {
    union { float f; uint i; } c; c.f = f; uint x = c.i;
    return (ushort)((x + 0x7FFFu + ((x >> 16) & 1u)) >> 16);   // RNE
}

// ---------------- in-degree count ----------------
__global__ __launch_bounds__(256) void k_count(const int* __restrict__ dst, int* __restrict__ cnt) {
    int i = blockIdx.x * blockDim.x + threadIdx.x;
    if (i < E_N) atomicAdd(&cnt[dst[i]], 1);
}

// ---------------- 3-kernel exclusive scan (1024 elems/block) ----------------
__global__ __launch_bounds__(256) void k_scan1(const int* __restrict__ cnt, int* __restrict__ rowptr,
                                               int* __restrict__ part) {
    __shared__ int sh[256];
    const int tid = threadIdx.x;
    const int base = blockIdx.x * 1024 + tid * 4;
    int v0 = (base + 0 < V_N) ? cnt[base + 0] : 0;
    int v1 = (base + 1 < V_N) ? cnt[base + 1] : 0;
    int v2 = (base + 2 < V_N) ? cnt[base + 2] : 0;
    int v3 = (base + 3 < V_N) ? cnt[base + 3] : 0;
    int s = v0 + v1 + v2 + v3;
    sh[tid] = s; __syncthreads();
    for (int off = 1; off < 256; off <<= 1) {
        int t = (tid >= off) ? sh[tid - off] : 0;
        __syncthreads();
        sh[tid] += t;
        __syncthreads();
    }
    int excl = sh[tid] - s;
    if (tid == 255) part[blockIdx.x] = sh[255];
    int run = excl;
    if (base + 0 < V_N) rowptr[base + 0] = run; run += v0;
    if (base + 1 < V_N) rowptr[base + 1] = run; run += v1;
    if (base + 2 < V_N) rowptr[base + 2] = run; run += v2;
    if (base + 3 < V_N) rowptr[base + 3] = run;
}

__global__ void k_scan2(const int* __restrict__ part, int* __restrict__ pex, int nb) {
    if (threadIdx.x == 0 && blockIdx.x == 0) {
        int run = 0;
        for (int i = 0; i < nb; ++i) { int t = part[i]; pex[i] = run; run += t; }
    }
}

__global__ __launch_bounds__(256) void k_scan3(int* __restrict__ rowptr, const int* __restrict__ pex,
                                               int* __restrict__ cursor) {
    int i = blockIdx.x * 256 + threadIdx.x;
    if (i < V_N) {
        int rp = rowptr[i] + pex[i >> 10];
        rowptr[i] = rp;
        cursor[i] = rp;
    }
    if (i == 0) rowptr[V_N] = E_N;
}

__global__ __launch_bounds__(256) void k_scatter(const int* __restrict__ dst, int* __restrict__ cursor,
                                                 int* __restrict__ perm) {
    int e = blockIdx.x * 256 + threadIdx.x;
    if (e < E_N) {
        int d = dst[e];
        int p = atomicAdd(&cursor[d], 1);
        perm[p] = e;
    }
}

// ---------------- node projection: h = concat(Z, meta) @ Wp + bp ----------------
__global__ __launch_bounds__(128) void k_nodeproj(const float* __restrict__ Z, const float* __restrict__ meta,
                                                  const float* __restrict__ W, const float* __restrict__ b,
                                                  float* __restrict__ h, ushort* __restrict__ hb) {
    __shared__ float rows[16][140];
    const int base = blockIdx.x * 16;
    const int tid = threadIdx.x;
    for (int idx = tid; idx < 16 * 138; idx += 128) {
        int r = idx / 138, c = idx - r * 138;
        int v = base + r;
        rows[r][c] = (c < 128) ? Z[(size_t)v * 128 + c] : meta[(size_t)v * 10 + (c - 128)];
    }
    __syncthreads();
    const int j = tid;
    float acc[16];
    float bj = b[j];
#pragma unroll
    for (int r = 0; r < 16; ++r) acc[r] = bj;
    const float4* r4 = (const float4*)&rows[0][0];
    for (int k4 = 0; k4 < 34; ++k4) {
        float w0 = W[(k4 * 4 + 0) * 128 + j];
        float w1 = W[(k4 * 4 + 1) * 128 + j];
        float w2 = W[(k4 * 4 + 2) * 128 + j];
        float w3 = W[(k4 * 4 + 3) * 128 + j];
#pragma unroll
        for (int r = 0; r < 16; ++r) {
            float4 rv = r4[r * 35 + k4];
            acc[r] = fmaf(rv.x, w0, acc[r]);
            acc[r] = fmaf(rv.y, w1, acc[r]);
            acc[r] = fmaf(rv.z, w2, acc[r]);
            acc[r] = fmaf(rv.w, w3, acc[r]);
        }
    }
    {
        float w0 = W[136 * 128 + j];
        float w1 = W[137 * 128 + j];
#pragma unroll
        for (int r = 0; r < 16; ++r) {
            acc[r] = fmaf(rows[r][136], w0, acc[r]);
            acc[r] = fmaf(rows[r][137], w1, acc[r]);
        }
    }
#pragma unroll
    for (int r = 0; r < 16; ++r) {
        size_t o = (size_t)(base + r) * 128 + j;
        h[o] = acc[r];
        hb[o] = f2bf(acc[r]);
    }
}

// ---------------- stage W[128][128] fp32 into frag-packed bf16 LDS ----------------
__device__ __forceinline__ void stage_B(const float* __restrict__ W, uint4* Bs4, int tid) {
    for (int slot = tid; slot < 2048; slot += 256) {
        int ks = slot >> 9;
        int ct = (slot >> 6) & 7;
        int l  = slot & 63;
        int k0 = ks * 32 + (l >> 4) * 8;
        int col = ct * 16 + (l & 15);
        const float* wp = W + (size_t)k0 * 128 + col;
        ushort u[8];
#pragma unroll
        for (int e = 0; e < 8; ++e) u[e] = f2bf(wp[(size_t)e * 128]);
        uint4 p;
        p.x = (uint)u[0] | ((uint)u[1] << 16);
        p.y = (uint)u[2] | ((uint)u[3] << 16);
        p.z = (uint)u[4] | ((uint)u[5] << 16);
        p.w = (uint)u[6] | ((uint)u[7] << 16);
        Bs4[slot] = p;
    }
}

// ---------------- GEMM1: tb = bf16(hb @ W1b + b1), MFMA ----------------
__global__ __launch_bounds__(256) void k_gemm1(const ushort* __restrict__ hb, const float* __restrict__ W,
                                               const float* __restrict__ b, ushort* __restrict__ tb) {
    __shared__ uint4 Bs4[2048];
    const int tid = threadIdx.x;
    stage_B(W, Bs4, tid);
    __syncthreads();
    const int lane = tid & 63, wid = tid >> 6;
    const int l15 = lane & 15, l4 = lane >> 4;
    float bcol[8];
#pragma unroll
    for (int ct = 0; ct < 8; ++ct) bcol[ct] = b[ct * 16 + l15];
    for (int tile = blockIdx.x; tile < NTILES; tile += gridDim.x) {
        const int rowA = tile * 64 + wid * 16 + l15;
        const uint4* ap = (const uint4*)(hb + (size_t)rowA * 128);
        f4_t acc[8];
#pragma unroll
        for (int ct = 0; ct < 8; ++ct) acc[ct] = (f4_t){bcol[ct], bcol[ct], bcol[ct], bcol[ct]};
#pragma unroll
        for (int ks = 0; ks < 4; ++ks) {
            union { uint4 u; bf8_t b; } ca; ca.u = ap[ks * 4 + l4];
#pragma unroll
            for (int ct = 0; ct < 8; ++ct) {
                union { uint4 u; bf8_t b; } cb; cb.u = Bs4[(ks * 8 + ct) * 64 + lane];
                acc[ct] = __builtin_amdgcn_mfma_f32_16x16x32_bf16(ca.b, cb.b, acc[ct], 0, 0, 0);
            }
        }
        const int rowC0 = tile * 64 + wid * 16 + l4 * 4;
#pragma unroll
        for (int ct = 0; ct < 8; ++ct) {
            int col = ct * 16 + l15;
#pragma unroll
            for (int r = 0; r < 4; ++r) {
                int row = rowC0 + r;
                if (row < V_N) tb[(size_t)row * 128 + col] = f2bf(acc[ct][r]);
            }
        }
    }
}

// ---------------- edge aggregation (CSR): S[v] = mean_e relu(tb[src] + ea@W1a), bf16 ----------------
#define EDGE_FMA(av, f0, f1, f2, f3)                                   \
    p0 = fmaf(av.x, w0[f0], p0); p1 = fmaf(av.x, w1[f0], p1);          \
    p0 = fmaf(av.y, w0[f1], p0); p1 = fmaf(av.y, w1[f1], p1);          \
    p0 = fmaf(av.z, w0[f2], p0); p1 = fmaf(av.z, w1[f2], p1);          \
    p0 = fmaf(av.w, w0[f3], p0); p1 = fmaf(av.w, w1[f3], p1);

__global__ __launch_bounds__(256) void k_edge_agg(const ushort* __restrict__ tb, const float* __restrict__ ea,
                                                  const int* __restrict__ src, const int* __restrict__ perm,
                                                  const int* __restrict__ rowptr, const float* __restrict__ W1a,
                                                  ushort* __restrict__ S) {
    const int lane = threadIdx.x & 63;
    const int wid = threadIdx.x >> 6;
    const int v = blockIdx.x * 4 + wid;
    if (v >= V_N) return;
    float w0[16], w1[16];
#pragma unroll
    for (int f = 0; f < 16; ++f) {
        float2 w = *(const float2*)(W1a + f * 128 + 2 * lane);
        w0[f] = w.x; w1[f] = w.y;
    }
    const int st = rowptr[v], en = rowptr[v + 1];
    float a0 = 0.f, a1 = 0.f;
    for (int i = st; i < en; ++i) {
        int e = perm[i];
        int s = src[e];
        uint tv = *(const uint*)(tb + (size_t)s * 128 + 2 * lane);
        float p0 = bf2f((ushort)(tv & 0xffffu));
        float p1 = bf2f((ushort)(tv >> 16));
        const float4* q = (const float4*)(ea + (size_t)e * 16);
        float4 e0 = q[0], e1 = q[1], e2 = q[2], e3 = q[3];
        EDGE_FMA(e0, 0, 1, 2, 3)
        EDGE_FMA(e1, 4, 5, 6, 7)
        EDGE_FMA(e2, 8, 9, 10, 11)
        EDGE_FMA(e3, 12, 13, 14, 15)
        a0 += fmaxf(p0, 0.f);
        a1 += fmaxf(p1, 0.f);
    }
    int dg = en - st;
    float inv = 1.f / (float)(dg > 1 ? dg : 1);
    uint outv = (uint)f2bf(a0 * inv) | ((uint)f2bf(a1 * inv) << 16);
    *(uint*)(S + (size_t)v * 128 + 2 * lane) = outv;
}

// ---------------- node update: h = LN(h + S@W2 + b2*mask), MFMA + fused LN ----------------
__global__ __launch_bounds__(256) void k_node_update(const ushort* __restrict__ S, float* __restrict__ h,
                                                     ushort* __restrict__ hb, const int* __restrict__ cnt,
                                                     const float* __restrict__ W2, const float* __restrict__ b2,
                                                     const float* __restrict__ g, const float* __restrict__ bt) {
    __shared__ uint4 Bs4[2048];
    const int tid = threadIdx.x;
    stage_B(W2, Bs4, tid);
    __syncthreads();
    const int lane = tid & 63, wid = tid >> 6;
    const int l15 = lane & 15, l4 = lane >> 4;
    float b2c[8], gc[8], btc[8];
#pragma unroll
    for (int ct = 0; ct < 8; ++ct) {
        int col = ct * 16 + l15;
        b2c[ct] = b2[col]; gc[ct] = g[col]; btc[ct] = bt[col];
    }
    for (int tile = blockIdx.x; tile < NTILES; tile += gridDim.x) {
        const int rowA = tile * 64 + wid * 16 + l15;
        const uint4* ap = (const uint4*)(S + (size_t)rowA * 128);
        f4_t acc[8];
#pragma unroll
        for (int ct = 0; ct < 8; ++ct) acc[ct] = (f4_t){0.f, 0.f, 0.f, 0.f};
#pragma unroll
        for (int ks = 0; ks < 4; ++ks) {
            union { uint4 u; bf8_t b; } ca; ca.u = ap[ks * 4 + l4];
#pragma unroll
            for (int ct = 0; ct < 8; ++ct) {
                union { uint4 u; bf8_t b; } cb; cb.u = Bs4[(ks * 8 + ct) * 64 + lane];
                acc[ct] = __builtin_amdgcn_mfma_f32_16x16x32_bf16(ca.b, cb.b, acc[ct], 0, 0, 0);
            }
        }
        const int rowC0 = tile * 64 + wid * 16 + l4 * 4;
        float mask[4];
#pragma unroll
        for (int r = 0; r < 4; ++r) {
            int row = rowC0 + r;
            int dg = (row < V_N) ? cnt[row] : 0;
            mask[r] = (dg > 0) ? 1.f : 0.f;
        }
        float x[8][4];
#pragma unroll
        for (int ct = 0; ct < 8; ++ct) {
            int col = ct * 16 + l15;
#pragma unroll
            for (int r = 0; r < 4; ++r) {
                float hv = h[(size_t)(rowC0 + r) * 128 + col];
                x[ct][r] = hv + acc[ct][r] + b2c[ct] * mask[r];
            }
        }
#pragma unroll
        for (int r = 0; r < 4; ++r) {
            float s = 0.f;
#pragma unroll
            for (int ct = 0; ct < 8; ++ct) s += x[ct][r];
            s += __shfl_xor(s, 1); s += __shfl_xor(s, 2);
            s += __shfl_xor(s, 4); s += __shfl_xor(s, 8);
            float mean = s * (1.f / 128.f);
            float vv = 0.f;
#pragma unroll
            for (int ct = 0; ct < 8; ++ct) { float d = x[ct][r] - mean; vv = fmaf(d, d, vv); }
            vv += __shfl_xor(vv, 1); vv += __shfl_xor(vv, 2);
            vv += __shfl_xor(vv, 4); vv += __shfl_xor(vv, 8);
            float rs = rsqrtf(vv * (1.f / 128.f) + LN_EPS);
            int row = rowC0 + r;
            bool ok = row < V_N;
#pragma unroll
            for (int ct = 0; ct < 8; ++ct) {
                int col = ct * 16 + l15;
                float y = (x[ct][r] - mean) * rs * gc[ct] + btc[ct];
                if (ok) {
                    size_t o = (size_t)row * 128 + col;
                    h[o] = y;
                    hb[o] = f2bf(y);
                }
            }
        }
    }
}

// ---------------- final: out = LN(h[cur] + props MLP) ----------------
__global__ __launch_bounds__(128) void k_final(const float* __restrict__ h, const int* __restrict__ cur,
                                               const float* __restrict__ veh,
                                               const float* __restrict__ pw1, const float* __restrict__ pb1,
                                               const float* __restrict__ pw2, const float* __restrict__ pb2,
                                               const float* __restrict__ g, const float* __restrict__ bt,
                                               float* __restrict__ out) {
    __shared__ float hid[128];
    __shared__ float red[2];
    const int i = blockIdx.x;
    const int j = threadIdx.x;
    float a = pb1[j];
#pragma unroll
    for (int f = 0; f < 8; ++f) a = fmaf(veh[i * 8 + f], pw1[f * 128 + j], a);
    hid[j] = fmaxf(a, 0.f);
    __syncthreads();
    float o = pb2[j] + h[(size_t)cur[i] * 128 + j];
    for (int k = 0; k < 128; ++k) o = fmaf(hid[k], pw2[k * 128 + j], o);
    const int lane = j & 63, wid = j >> 6;
    float s = o;
#pragma unroll
    for (int off = 32; off > 0; off >>= 1) s += __shfl_xor(s, off);
    if (lane == 0) red[wid] = s;
    __syncthreads();
    float mean = (red[0] + red[1]) * (1.f / 128.f);
    __syncthreads();
    float d = o - mean;
    float vv = d * d;
#pragma unroll
    for (int off = 32; off > 0; off >>= 1) vv += __shfl_xor(vv, off);
    if (lane == 0) red[wid] = vv;
    __syncthreads();
    float var = (red[0] + red[1]) * (1.f / 128.f);
    float r = rsqrtf(var + LN_EPS);
    out[i * 128 + j] = d * r * g[j] + bt[j];
}

extern "C" void kernel_launch(void* const* d_in, const int* in_sizes, int n_in,
                              void* d_out, int out_size, void* d_ws, size_t ws_size,
                              hipStream_t stream) {
    const float* Z    = (const float*)d_in[0];
    const float* meta = (const float*)d_in[1];
    const float* veh  = (const float*)d_in[2];
    const float* ea   = (const float*)d_in[3];
    const int*   esrc = (const int*)d_in[4];
    const int*   edst = (const int*)d_in[5];
    const int*   cur  = (const int*)d_in[6];
    const float* npw  = (const float*)d_in[7];
    const float* npb  = (const float*)d_in[8];
    const float* w1   = (const float*)d_in[9];
    const float* b1   = (const float*)d_in[10];
    const float* w2   = (const float*)d_in[11];
    const float* b2   = (const float*)d_in[12];
    const float* lng  = (const float*)d_in[13];
    const float* lnb  = (const float*)d_in[14];
    const float* pw1  = (const float*)d_in[15];
    const float* pb1  = (const float*)d_in[16];
    const float* pw2  = (const float*)d_in[17];
    const float* pb2  = (const float*)d_in[18];
    const float* rog  = (const float*)d_in[19];
    const float* rob  = (const float*)d_in[20];

    float*  h  = (float*)d_ws;                      // [VP][128] f32
    ushort* hb = (ushort*)(h + (size_t)VP * 128);   // [VP][128] bf16
    ushort* tb = hb + (size_t)VP * 128;             // [VP][128] bf16
    ushort* S  = tb + (size_t)VP * 128;             // [VP][128] bf16
    int* cnt    = (int*)(S + (size_t)VP * 128);     // [VP]
    int* rowptr = cnt + VP;                         // [V+1]
    int* cursor = rowptr + VP;                      // [VP]
    int* perm   = cursor + VP;                      // [E]
    int* part   = perm + E_N;                       // [256]
    int* pex    = part + 256;                       // [256]
    float* out = (float*)d_out;

    const int NB = (V_N + 1023) / 1024;  // 98

    hipMemsetAsync(cnt, 0, VP * sizeof(int), stream);
    k_count<<<(E_N + 255) / 256, 256, 0, stream>>>(edst, cnt);
    k_scan1<<<NB, 256, 0, stream>>>(cnt, rowptr, part);
    k_scan2<<<1, 64, 0, stream>>>(part, pex, NB);
    k_scan3<<<(V_N + 255) / 256, 256, 0, stream>>>(rowptr, pex, cursor);
    k_scatter<<<(E_N + 255) / 256, 256, 0, stream>>>(edst, cursor, perm);
    k_nodeproj<<<V_N / 16, 128, 0, stream>>>(Z, meta, npw, npb, h, hb);

    for (int l = 0; l < 2; ++l) {
        const float* W1b = w1 + (size_t)l * 144 * 128;
        const float* W1a = W1b + 128 * 128;
        k_gemm1<<<1024, 256, 0, stream>>>(hb, W1b, b1 + l * 128, tb);
        k_edge_agg<<<(V_N + 3) / 4, 256, 0, stream>>>(tb, ea, esrc, perm, rowptr, W1a, S);
        k_node_update<<<1024, 256, 0, stream>>>(S, h, hb, cnt, w2 + (size_t)l * 128 * 128,
                                                b2 + l * 128, lng + l * 128, lnb + l * 128);
    }
    k_final<<<NVEH, 128, 0, stream>>>(h, cur, veh, pw1, pb1, pw2, pb2, rog, rob, out);
}